// Round 4
// baseline (1167.148 us; speedup 1.0000x reference)
//
#include <hip/hip_runtime.h>
#include <hip/hip_bf16.h>

typedef __attribute__((ext_vector_type(4))) float f32x4;
typedef __attribute__((ext_vector_type(8))) short bf16x8;
typedef unsigned short u16;

#define BN_EPS 1e-5f
#define WS_NEEDED 88104960ull   // high-water mark of d_ws usage in bytes

// ---------- helpers ----------

__device__ __forceinline__ u16 f2bf(float f) {
  union { float f; unsigned u; } v; v.f = f;
  unsigned r = v.u + 0x7FFFu + ((v.u >> 16) & 1u);   // round-to-nearest-even
  return (u16)(r >> 16);
}

__device__ __forceinline__ void gl_lds16(const void* g, void* l) {
  // async global->LDS, 16B per lane; LDS dest is wave-uniform base + lane*16
  __builtin_amdgcn_global_load_lds((const __attribute__((address_space(1))) void*)g,
                                   (__attribute__((address_space(3))) void*)l,
                                   16, 0, 0);
}

// ---------- f32 -> bf16 convert (vectorized x8) ----------

__global__ void cvt_kernel(const float* __restrict__ in, u16* __restrict__ out, int n) {
  int i = (blockIdx.x * 256 + threadIdx.x) * 8;
  if (i + 8 > n) return;
  const float4* p = (const float4*)(in + i);
  float4 a = p[0], b = p[1];
  bf16x8 v;
  v[0] = (short)f2bf(a.x); v[1] = (short)f2bf(a.y); v[2] = (short)f2bf(a.z); v[3] = (short)f2bf(a.w);
  v[4] = (short)f2bf(b.x); v[5] = (short)f2bf(b.y); v[6] = (short)f2bf(b.z); v[7] = (short)f2bf(b.w);
  *(bf16x8*)(out + i) = v;
}

// ---------- transpose (+convert) : in[R][C] -> out[C][R] bf16 ----------

template <typename TIN>
__global__ void tcvt_kernel(const TIN* __restrict__ in, u16* __restrict__ out, int R, int C) {
  __shared__ u16 tile[32][33];
  const int bx = blockIdx.x * 32;   // col of in
  const int by = blockIdx.y * 32;   // row of in
  const int tx = threadIdx.x, ty = threadIdx.y;   // 32 x 8
#pragma unroll
  for (int i = 0; i < 32; i += 8) {
    TIN val = in[(size_t)(by + ty + i) * C + bx + tx];
    if constexpr (sizeof(TIN) == 4) tile[ty + i][tx] = f2bf((float)val);
    else                            tile[ty + i][tx] = (u16)val;
  }
  __syncthreads();
#pragma unroll
  for (int i = 0; i < 32; i += 8)
    out[(size_t)(bx + ty + i) * R + by + tx] = tile[tx][ty + i];
}

// ---------- matvec: out[row] = dot(M[row,:K], x) + add[row] (f32) ----------

__global__ void matvec_kernel(const float* __restrict__ M, int ld,
                              const float* __restrict__ x, const float* __restrict__ add,
                              float* __restrict__ out, int K) {
  __shared__ float red[4];
  const int row = blockIdx.x;
  const float* mp = M + (size_t)row * ld;
  float s = 0.f;
  for (int k = threadIdx.x; k < K; k += 256) s += mp[k] * x[k];
#pragma unroll
  for (int off = 32; off > 0; off >>= 1) s += __shfl_down(s, off);
  if ((threadIdx.x & 63) == 0) red[threadIdx.x >> 6] = s;
  __syncthreads();
  if (threadIdx.x == 0) out[row] = red[0] + red[1] + red[2] + red[3] + add[row];
}

// ---------- bf16 GEMM-BT: C[M,N] = A[M,K] @ B[N,K]^T, all row-major, bf16 out ----------
// 128x128 tile, BK=64, 256 threads (2x2 waves of 64x64), mfma 16x16x32 bf16.

__global__ __launch_bounds__(256, 2)
void gemm_bt_bf16(const u16* __restrict__ A, int lda,
                  const u16* __restrict__ B, int ldb,
                  u16* __restrict__ C, int ldc, int K, int ntn) {
  __shared__ u16 As[128 * 64];
  __shared__ u16 Bs[128 * 64];
  int bid = blockIdx.x;
  if ((gridDim.x & 7) == 0) { int cpx = (int)gridDim.x >> 3; bid = (bid & 7) * cpx + (bid >> 3); }
  const int tm = bid / ntn, tn = bid % ntn;
  const int tid = threadIdx.x;
  const int w = tid >> 6, lane = tid & 63;
  const int fr = lane & 15, fq = lane >> 4;
  const int wr = w >> 1, wc = w & 1;

  f32x4 acc[4][4] = {};
  const u16* Ab = A + (size_t)tm * 128 * lda;
  const u16* Bb = B + (size_t)tn * 128 * ldb;

  for (int kt = 0; kt < K; kt += 64) {
#pragma unroll
    for (int p = 0; p < 4; ++p) {
      const int chunk = p * 256 + tid;
      const int r = chunk >> 3, c8 = chunk & 7;
      gl_lds16(Ab + (size_t)r * lda + kt + c8 * 8, (char*)As + p * 4096 + w * 1024);
      gl_lds16(Bb + (size_t)r * ldb + kt + c8 * 8, (char*)Bs + p * 4096 + w * 1024);
    }
    __syncthreads();
#pragma unroll
    for (int kk = 0; kk < 2; ++kk) {
      bf16x8 a[4], b[4];
#pragma unroll
      for (int m = 0; m < 4; ++m)
        a[m] = *(const bf16x8*)&As[(wr * 64 + m * 16 + fr) * 64 + kk * 32 + fq * 8];
#pragma unroll
      for (int n = 0; n < 4; ++n)
        b[n] = *(const bf16x8*)&Bs[(wc * 64 + n * 16 + fr) * 64 + kk * 32 + fq * 8];
#pragma unroll
      for (int m = 0; m < 4; ++m)
#pragma unroll
        for (int n = 0; n < 4; ++n)
          acc[m][n] = __builtin_amdgcn_mfma_f32_16x16x32_bf16(a[m], b[n], acc[m][n], 0, 0, 0);
    }
    __syncthreads();
  }
  // epilogue: C/D layout col=lane&15, row=(lane>>4)*4+reg
#pragma unroll
  for (int m = 0; m < 4; ++m) {
    const int row0 = tm * 128 + wr * 64 + m * 16 + fq * 4;
#pragma unroll
    for (int n = 0; n < 4; ++n) {
      const int col = tn * 128 + wc * 64 + n * 16 + fr;
#pragma unroll
      for (int r = 0; r < 4; ++r)
        C[(size_t)(row0 + r) * ldc + col] = f2bf(acc[m][n][r]);
    }
  }
}

// ---------- main fused kernel ----------
// out[b][j] = BNReLU( sum_k kmer[b][k]*Wbig1[j][k] + sum_k cov[b][k]*Wbig2[j][k] + btot[j] )
// M=16384, N=2048, K1=4096, K2=1024. A operands f32 (reg-staged->bf16), B bf16 via global_load_lds.

__global__ __launch_bounds__(256, 2)
void fused_main_kernel(const float* __restrict__ A1, const u16* __restrict__ B1,
                       const float* __restrict__ A2, const u16* __restrict__ B2,
                       const float* __restrict__ btot, const float* __restrict__ gamma,
                       const float* __restrict__ beta, const float* __restrict__ rmean,
                       const float* __restrict__ rvar, float* __restrict__ out) {
  __shared__ u16 As[128 * 64];
  __shared__ u16 Bs[128 * 64];
  int bid = blockIdx.x;
  { const int cpx = (int)gridDim.x >> 3; bid = (bid & 7) * cpx + (bid >> 3); }  // 2048 % 8 == 0
  const int tm = bid >> 4, tn = bid & 15;   // ntn = 16
  const int tid = threadIdx.x;
  const int w = tid >> 6, lane = tid & 63;
  const int fr = lane & 15, fq = lane >> 4;
  const int wr = w >> 1, wc = w & 1;

  f32x4 acc[4][4] = {};

#pragma unroll
  for (int phase = 0; phase < 2; ++phase) {
    const float* A = phase ? A2 : A1;
    const u16* B = phase ? B2 : B1;
    const int K = phase ? 1024 : 4096;       // lda == ldb == K for both phases
    const float* Ab = A + (size_t)tm * 128 * K;
    const u16* Bb = B + (size_t)tn * 128 * K;
    for (int kt = 0; kt < K; kt += 64) {
#pragma unroll
      for (int p = 0; p < 4; ++p) {
        const int chunk = p * 256 + tid;
        const int r = chunk >> 3, c8 = chunk & 7;
        gl_lds16(Bb + (size_t)r * K + kt + c8 * 8, (char*)Bs + p * 4096 + w * 1024);
        const float4* sa = (const float4*)(Ab + (size_t)r * K + kt + c8 * 8);
        float4 lo = sa[0], hi = sa[1];
        bf16x8 v;
        v[0] = (short)f2bf(lo.x); v[1] = (short)f2bf(lo.y);
        v[2] = (short)f2bf(lo.z); v[3] = (short)f2bf(lo.w);
        v[4] = (short)f2bf(hi.x); v[5] = (short)f2bf(hi.y);
        v[6] = (short)f2bf(hi.z); v[7] = (short)f2bf(hi.w);
        *(bf16x8*)&As[chunk * 8] = v;        // ds_write_b128, linear layout
      }
      __syncthreads();
#pragma unroll
      for (int kk = 0; kk < 2; ++kk) {
        bf16x8 a[4], b[4];
#pragma unroll
        for (int m = 0; m < 4; ++m)
          a[m] = *(const bf16x8*)&As[(wr * 64 + m * 16 + fr) * 64 + kk * 32 + fq * 8];
#pragma unroll
        for (int n = 0; n < 4; ++n)
          b[n] = *(const bf16x8*)&Bs[(wc * 64 + n * 16 + fr) * 64 + kk * 32 + fq * 8];
#pragma unroll
        for (int m = 0; m < 4; ++m)
#pragma unroll
          for (int n = 0; n < 4; ++n)
            acc[m][n] = __builtin_amdgcn_mfma_f32_16x16x32_bf16(a[m], b[n], acc[m][n], 0, 0, 0);
      }
      __syncthreads();
    }
  }

  // epilogue: + b_tot, BatchNorm (eval), ReLU, f32 store
#pragma unroll
  for (int n = 0; n < 4; ++n) {
    const int col = tn * 128 + wc * 64 + n * 16 + fr;
    const float bias = btot[col];
    const float mu = rmean[col];
    const float sc = gamma[col] * rsqrtf(rvar[col] + BN_EPS);
    const float bt = beta[col];
#pragma unroll
    for (int m = 0; m < 4; ++m) {
      const int row0 = tm * 128 + wr * 64 + m * 16 + fq * 4;
#pragma unroll
      for (int r = 0; r < 4; ++r) {
        float y = acc[m][n][r] + bias;
        y = (y - mu) * sc + bt;
        out[(size_t)(row0 + r) * 2048 + col] = fmaxf(y, 0.f);
      }
    }
  }
}

// ---------- launch ----------

extern "C" void kernel_launch(void* const* d_in, const int* in_sizes, int n_in,
                              void* d_out, int out_size, void* d_ws, size_t ws_size,
                              hipStream_t stream) {
  // Diagnostic guard: if the harness workspace is smaller than our high-water
  // mark, launch NOTHING. Output stays zeroed -> clean absmax failure report
  // (instead of an OOB write that could fault the GPU / kill the container).
  if (ws_size < WS_NEEDED) return;

  const float* kmer = (const float*)d_in[0];
  const float* cov  = (const float*)d_in[1];
  const float* Wk   = (const float*)d_in[2];
  const float* bk   = (const float*)d_in[3];
  const float* Wc   = (const float*)d_in[4];
  const float* bc   = (const float*)d_in[5];
  const float* Wv   = (const float*)d_in[6];
  const float* bv   = (const float*)d_in[7];
  const float* Wo   = (const float*)d_in[8];
  const float* bo   = (const float*)d_in[9];
  const float* Wf   = (const float*)d_in[10];
  const float* bf_  = (const float*)d_in[11];
  const float* gam  = (const float*)d_in[12];
  const float* bet  = (const float*)d_in[13];
  const float* rmu  = (const float*)d_in[14];
  const float* rvr  = (const float*)d_in[15];
  float* out = (float*)d_out;

  char* ws = (char*)d_ws;
  u16* wv_b  = (u16*)(ws + 0);          // 2048x2048 bf16
  u16* wo_b  = (u16*)(ws + 8388608);    // 2048x2048
  u16* wf_b  = (u16*)(ws + 16777216);   // 2048x4096
  u16* wkT   = (u16*)(ws + 33554432);   // 4096x2048 (= Wk^T)
  u16* wcT   = (u16*)(ws + 50331648);   // 1024x2048 (= Wc^T)
  u16* R1    = (u16*)(ws + 54525952);   // 1024x2048 = (Wv Wc)^T
  u16* R2    = (u16*)(ws + 58720256);   // 1024x2048 = (Wo Wv Wc)^T
  u16* R3    = (u16*)(ws + 62914560);   // 1024x2048 = (Wf2 Wo Wv Wc)^T
  u16* wbig2 = (u16*)(ws + 67108864);   // 2048x1024 = Wf2 Wo Wv Wc
  u16* wbig1 = (u16*)(ws + 71303168);   // 2048x4096 = Wf1 Wk
  float* t1  = (float*)(ws + 88080384); // 2048
  float* t2  = (float*)(ws + 88088576); // 2048
  float* btot= (float*)(ws + 88096768); // 2048

  // convert weights to bf16
  cvt_kernel<<<2048, 256, 0, stream>>>(Wv, wv_b, 2048 * 2048);
  cvt_kernel<<<2048, 256, 0, stream>>>(Wo, wo_b, 2048 * 2048);
  cvt_kernel<<<4096, 256, 0, stream>>>(Wf, wf_b, 2048 * 4096);
  tcvt_kernel<float><<<dim3(128, 64), dim3(32, 8), 0, stream>>>(Wk, wkT, 2048, 4096);
  tcvt_kernel<float><<<dim3(32, 64),  dim3(32, 8), 0, stream>>>(Wc, wcT, 2048, 1024);

  // weight-product GEMMs (all K=2048):
  // R1 = WcT @ Wv^T ; R2 = R1 @ Wo^T ; R3 = R2 @ Wf2^T ; wbig1 = Wf1 @ WkT^T
  gemm_bt_bf16<<<8 * 16, 256, 0, stream>>>(wcT, 2048, wv_b, 2048, R1, 2048, 2048, 16);
  gemm_bt_bf16<<<8 * 16, 256, 0, stream>>>(R1, 2048, wo_b, 2048, R2, 2048, 2048, 16);
  gemm_bt_bf16<<<8 * 16, 256, 0, stream>>>(R2, 2048, wf_b + 2048, 4096, R3, 2048, 2048, 16);
  gemm_bt_bf16<<<16 * 32, 256, 0, stream>>>(wf_b, 4096, wkT, 2048, wbig1, 4096, 2048, 32);
  tcvt_kernel<u16><<<dim3(64, 32), dim3(32, 8), 0, stream>>>(R3, wbig2, 1024, 2048);

  // effective bias: btot = Wf1@bk + Wf2@(Wo@(Wv@bc + bv) + bo) + bf
  matvec_kernel<<<2048, 256, 0, stream>>>(Wv, 2048, bc, bv, t1, 2048);
  matvec_kernel<<<2048, 256, 0, stream>>>(Wo, 2048, t1, bo, t2, 2048);
  matvec_kernel<<<2048, 256, 0, stream>>>(Wf + 2048, 4096, t2, bf_, btot, 2048);
  matvec_kernel<<<2048, 256, 0, stream>>>(Wf, 4096, bk, btot, btot, 2048);

  // fused main GEMM + BN + ReLU
  fused_main_kernel<<<128 * 16, 256, 0, stream>>>(kmer, wbig1, cov, wbig2,
                                                  btot, gam, bet, rmu, rvr, out);
}